// Round 1
// baseline (289.300 us; speedup 1.0000x reference)
//
#include <hip/hip_runtime.h>
#include <hip/hip_bf16.h>

#define BB 256
#define NIN 1024
#define NL 128
#define NSTEPS 256
#define TM 32

typedef __attribute__((ext_vector_type(8))) short bf16x8_t;
typedef __attribute__((ext_vector_type(4))) float f32x4_t;

__device__ inline unsigned short f2bf(float f) {
    __hip_bfloat16 h = __float2bfloat16(f);
    return *reinterpret_cast<unsigned short*>(&h);
}

// ---------------- K1: latent0 = x @ F ; L1 = latent0 @ T -------------------
__global__ __launch_bounds__(128) void k_init(const float* __restrict__ x,
                                              const float* __restrict__ tf,
                                              const float* __restrict__ tr,
                                              float* __restrict__ lats) {
    __shared__ float xrow[NIN];
    __shared__ float l0[NL];
    int b = blockIdx.x;
    int t = threadIdx.x;  // 128 threads
    const float4* xs = (const float4*)(x + (size_t)b * NIN);
    for (int i = t; i < NIN / 4; i += 128) ((float4*)xrow)[i] = xs[i];
    __syncthreads();
    float acc = 0.f;
#pragma unroll 8
    for (int i = 0; i < NIN; ++i) acc += xrow[i] * tf[i * NL + t];
    l0[t] = acc;
    __syncthreads();
    float acc2 = 0.f;
#pragma unroll 8
    for (int k = 0; k < NL; ++k) acc2 += l0[k] * tr[k * NL + t];
    lats[((size_t)b * NSTEPS + 0) * NL + t] = acc2;
}

// ---------------- K2: doubling stage --------------------------------------
// apply blocks: for rows r in [0, k*B): (b = r>>lk, s = r & (k-1))
//   lats[b][s+k] = lats[b][s] @ P      (P = T^k, staged in LDS)
// square blocks (appended): Pnext = P @ P
__global__ __launch_bounds__(256) void k_stage(float* __restrict__ lats,
                                               const float* __restrict__ P,
                                               float* __restrict__ Pnext,
                                               int lk, int napply, int do_square) {
    __shared__ float Pl[NL * NL];       // 64 KB
    __shared__ float At[NL][TM + 4];    // [k][m] transposed, pad->36 (18 KB)
    int t = threadIdx.x;
    int k = 1 << lk;

    // stage P into LDS (coalesced float4)
    {
        const float4* Ps = (const float4*)P;
        float4* Pld = (float4*)Pl;
        for (int i = t; i < NL * NL / 4; i += 256) Pld[i] = Ps[i];
    }
    bool is_sq = ((int)blockIdx.x >= napply);
    int blk = is_sq ? ((int)blockIdx.x - napply) : (int)blockIdx.x;
    int r0 = blk * TM;

    // stage A tile transposed: At[kk][m] = row(r0+m)[kk]
    for (int idx = t; idx < TM * NL; idx += 256) {
        int m = idx >> 7;
        int kk = idx & 127;
        int r = r0 + m;
        const float* src;
        if (is_sq) {
            src = P + (size_t)r * NL;
        } else {
            int bb = r >> lk;
            int ss = r & (k - 1);
            src = lats + ((size_t)bb * NSTEPS + ss) * NL;
        }
        At[kk][m] = src[kk];
    }
    __syncthreads();

    int j = t & 127;
    int rg = t >> 7;  // wave-uniform (0 for waves 0-1, 1 for waves 2-3)
    float acc[16];
#pragma unroll
    for (int i = 0; i < 16; ++i) acc[i] = 0.f;

#pragma unroll 2
    for (int kk = 0; kk < NL; ++kk) {
        float bv = Pl[kk * NL + j];
        const f32x4_t* ap = (const f32x4_t*)&At[kk][rg * 16];
        f32x4_t a0 = ap[0], a1 = ap[1], a2 = ap[2], a3 = ap[3];
        acc[0] += a0[0] * bv;  acc[1] += a0[1] * bv;
        acc[2] += a0[2] * bv;  acc[3] += a0[3] * bv;
        acc[4] += a1[0] * bv;  acc[5] += a1[1] * bv;
        acc[6] += a1[2] * bv;  acc[7] += a1[3] * bv;
        acc[8] += a2[0] * bv;  acc[9] += a2[1] * bv;
        acc[10] += a2[2] * bv; acc[11] += a2[3] * bv;
        acc[12] += a3[0] * bv; acc[13] += a3[1] * bv;
        acc[14] += a3[2] * bv; acc[15] += a3[3] * bv;
    }

#pragma unroll
    for (int i = 0; i < 16; ++i) {
        int r = r0 + rg * 16 + i;
        if (is_sq) {
            Pnext[(size_t)r * NL + j] = acc[i];
        } else {
            int bb = r >> lk;
            int ss = r & (k - 1);
            lats[((size_t)bb * NSTEPS + ss + k) * NL + j] = acc[i];
        }
    }
}

// ---------------- K3: convert lats + transform to bf16 ---------------------
__global__ __launch_bounds__(256) void k_convert(const float* __restrict__ latsf,
                                                 const float* __restrict__ tf,
                                                 unsigned short* __restrict__ latsb,
                                                 unsigned short* __restrict__ tfb) {
    const long NLAT4 = (long)BB * NSTEPS * NL / 4;  // 2,097,152
    const long NTF4 = (long)NIN * NL / 4;           // 32,768
    long idx = (long)blockIdx.x * 256 + threadIdx.x;
    if (idx < NLAT4) {
        float4 v = ((const float4*)latsf)[idx];
        ushort4 o;
        o.x = f2bf(v.x); o.y = f2bf(v.y); o.z = f2bf(v.z); o.w = f2bf(v.w);
        ((ushort4*)latsb)[idx] = o;
    } else if (idx < NLAT4 + NTF4) {
        long i2 = idx - NLAT4;
        float4 v = ((const float4*)tf)[i2];
        ushort4 o;
        o.x = f2bf(v.x); o.y = f2bf(v.y); o.z = f2bf(v.z); o.w = f2bf(v.w);
        ((ushort4*)tfb)[i2] = o;
    }
}

// ---------------- K4: projection out_b = F @ lats_b^T (bf16 MFMA, NT) -----
// grid = B * 8 (n-tiles of 128) * 2 (s-tiles of 128); block 256 (4 waves)
__global__ __launch_bounds__(256) void k_proj(const unsigned short* __restrict__ tfb,
                                              const unsigned short* __restrict__ latsb,
                                              float* __restrict__ out) {
    int bid = blockIdx.x;
    int st = bid & 1;
    int mt = (bid >> 1) & 7;
    int b = bid >> 4;

    __shared__ __align__(16) char lA[128 * 256];  // swizzled bf16 [128][128]
    __shared__ __align__(16) char lB[128 * 256];

    int t = threadIdx.x;
    const unsigned short* Ag = tfb + (size_t)(mt * 128) * NL;
    const unsigned short* Bg = latsb + ((size_t)b * NSTEPS + st * 128) * NL;

    // stage both tiles: 2048 x 16B chunks each, XOR-swizzled rows
    for (int i = t; i < 2048; i += 256) {
        int row = i >> 4, c = i & 15;
        int sw = (c * 16) ^ ((row & 7) << 4);
        *(bf16x8_t*)(lA + row * 256 + sw) =
            *(const bf16x8_t*)(Ag + (size_t)row * NL + c * 8);
        *(bf16x8_t*)(lB + row * 256 + sw) =
            *(const bf16x8_t*)(Bg + (size_t)row * NL + c * 8);
    }
    __syncthreads();

    int w = t >> 6, lane = t & 63;
    int wn = (w >> 1) * 64;   // wave n-offset within 128 tile
    int wsd = (w & 1) * 64;   // wave s-offset
    int r = lane & 15, g = lane >> 4;

    f32x4_t acc[4][4];
#pragma unroll
    for (int m = 0; m < 4; ++m)
#pragma unroll
        for (int n = 0; n < 4; ++n) acc[m][n] = (f32x4_t){0.f, 0.f, 0.f, 0.f};

#pragma unroll
    for (int kk = 0; kk < 4; ++kk) {
        int c16 = kk * 4 + g;
        bf16x8_t a[4], bv[4];
#pragma unroll
        for (int m = 0; m < 4; ++m) {
            int rowA = wn + m * 16 + r;
            a[m] = *(const bf16x8_t*)(lA + rowA * 256 + ((c16 * 16) ^ ((rowA & 7) << 4)));
            int rowB = wsd + m * 16 + r;
            bv[m] = *(const bf16x8_t*)(lB + rowB * 256 + ((c16 * 16) ^ ((rowB & 7) << 4)));
        }
#pragma unroll
        for (int m = 0; m < 4; ++m)
#pragma unroll
            for (int n = 0; n < 4; ++n)
                acc[m][n] = __builtin_amdgcn_mfma_f32_16x16x32_bf16(a[m], bv[n], acc[m][n], 0, 0, 0);
    }

    float* ob = out + (size_t)b * NIN * NSTEPS;
#pragma unroll
    for (int m = 0; m < 4; ++m) {
#pragma unroll
        for (int n = 0; n < 4; ++n) {
#pragma unroll
            for (int i = 0; i < 4; ++i) {
                int gn = mt * 128 + wn + m * 16 + g * 4 + i;
                int gs = st * 128 + wsd + n * 16 + r;
                ob[(size_t)gn * NSTEPS + gs] = acc[m][n][i];
            }
        }
    }
}

extern "C" void kernel_launch(void* const* d_in, const int* in_sizes, int n_in,
                              void* d_out, int out_size, void* d_ws, size_t ws_size,
                              hipStream_t stream) {
    const float* x = (const float*)d_in[0];
    const float* tf = (const float*)d_in[1];
    const float* tr = (const float*)d_in[2];
    float* out = (float*)d_out;

    float* lats = (float*)d_ws;                       // [B][S][NL] f32 (33.5 MB)
    float* P0 = lats + (size_t)BB * NSTEPS * NL;      // 64 KB
    float* P1 = P0 + NL * NL;                         // 64 KB
    unsigned short* latsb = (unsigned short*)(P1 + NL * NL);  // bf16 lats (16.8 MB)
    unsigned short* tfb = latsb + (size_t)BB * NSTEPS * NL;   // bf16 transform

    k_init<<<BB, 128, 0, stream>>>(x, tf, tr, lats);

    const float* Pcur = tr;
    float* bufs[2] = {P0, P1};
    int bi = 0;
    for (int k = 1; k < NSTEPS; k <<= 1) {
        int lk = __builtin_ctz(k);
        int napply = (k * BB) / TM;  // 8k blocks
        int do_sq = (2 * k < NSTEPS) ? 1 : 0;
        int grid = napply + (do_sq ? (NL / TM) : 0);
        k_stage<<<grid, 256, 0, stream>>>(lats, Pcur, bufs[bi], lk, napply, do_sq);
        if (do_sq) { Pcur = bufs[bi]; bi ^= 1; }
    }

    k_convert<<<8320, 256, 0, stream>>>(lats, tf, latsb, tfb);
    k_proj<<<BB * 16, 256, 0, stream>>>(tfb, latsb, out);
}

// Round 2
// 253.208 us; speedup vs baseline: 1.1425x; 1.1425x over previous
//
#include <hip/hip_runtime.h>
#include <hip/hip_bf16.h>

#define BB 256
#define NIN 1024
#define NL 128
#define NSTEPS 256
#define MS 16384  // one 128x128 matrix slot (floats)

typedef __attribute__((ext_vector_type(8))) short bf16x8_t;
typedef __attribute__((ext_vector_type(4))) float f32x4_t;

__device__ inline unsigned short f2bf(float f) {
    __hip_bfloat16 h = __float2bfloat16(f);
    return *reinterpret_cast<unsigned short*>(&h);
}

// ---------------- K1: latent0 = x @ F  [256,128] f32 ----------------------
__global__ __launch_bounds__(128) void k_init(const float* __restrict__ x,
                                              const float* __restrict__ tf,
                                              float* __restrict__ lat0) {
    __shared__ float xrow[NIN];
    int b = blockIdx.x;
    int t = threadIdx.x;  // 128 threads
    const float4* xs = (const float4*)(x + (size_t)b * NIN);
    for (int i = t; i < NIN / 4; i += 128) ((float4*)xrow)[i] = xs[i];
    __syncthreads();
    float acc = 0.f;
#pragma unroll 8
    for (int i = 0; i < NIN; ++i) acc += xrow[i] * tf[i * NL + t];
    lat0[(size_t)b * NL + t] = acc;
}

// ---------------- K2: power-chain level: D_i = A_i @ B (f32, 128x128) -----
// grid = nmat*4; block computes 32 rows of D_i.
__global__ __launch_bounds__(256) void k_pmm(const float* __restrict__ A0,
                                             const float* __restrict__ Bm,
                                             float* __restrict__ D0) {
    int i = blockIdx.x >> 2, rt = blockIdx.x & 3;
    const float* A = A0 + (size_t)i * MS;
    float* D = D0 + (size_t)i * MS;
    int r0 = rt * 32;
    __shared__ float Bl[NL * NL];     // 64 KB
    __shared__ float At[NL][36];      // transposed A tile, 18 KB
    int t = threadIdx.x;
    for (int idx = t; idx < MS / 4; idx += 256)
        ((float4*)Bl)[idx] = ((const float4*)Bm)[idx];
    for (int idx = t; idx < 32 * NL; idx += 256) {
        int m = idx >> 7, kk = idx & 127;
        At[kk][m] = A[(size_t)(r0 + m) * NL + kk];
    }
    __syncthreads();
    int j = t & 127, rg = t >> 7;
    float acc[16];
#pragma unroll
    for (int q = 0; q < 16; ++q) acc[q] = 0.f;
#pragma unroll 2
    for (int kk = 0; kk < NL; ++kk) {
        float bv = Bl[kk * NL + j];
        const f32x4_t* ap = (const f32x4_t*)&At[kk][rg * 16];
        f32x4_t a0 = ap[0], a1 = ap[1], a2 = ap[2], a3 = ap[3];
        acc[0] += a0[0] * bv;  acc[1] += a0[1] * bv;
        acc[2] += a0[2] * bv;  acc[3] += a0[3] * bv;
        acc[4] += a1[0] * bv;  acc[5] += a1[1] * bv;
        acc[6] += a1[2] * bv;  acc[7] += a1[3] * bv;
        acc[8] += a2[0] * bv;  acc[9] += a2[1] * bv;
        acc[10] += a2[2] * bv; acc[11] += a2[3] * bv;
        acc[12] += a3[0] * bv; acc[13] += a3[1] * bv;
        acc[14] += a3[2] * bv; acc[15] += a3[3] * bv;
    }
#pragma unroll
    for (int q = 0; q < 16; ++q)
        D[(size_t)(r0 + rg * 16 + q) * NL + j] = acc[q];
}

// ---------------- K3: checkpoints C_j = bf16(latent0 @ T^{16j}) -----------
// grid = 16j * 8 rowtiles; C layout [j][b][m] bf16
__global__ __launch_bounds__(256) void k_C(const float* __restrict__ lat0,
                                           const float* __restrict__ W,
                                           unsigned short* __restrict__ C) {
    int j = blockIdx.x >> 3, rt = blockIdx.x & 7;
    int r0 = rt * 32;
    int t = threadIdx.x;
    unsigned short* Cj = C + (size_t)j * BB * NL;
    if (j == 0) {
        for (int idx = t; idx < 32 * NL; idx += 256) {
            int row = idx >> 7, col = idx & 127;
            Cj[(size_t)(r0 + row) * NL + col] = f2bf(lat0[(size_t)(r0 + row) * NL + col]);
        }
        return;
    }
    const float* Bm = W + (size_t)(14 + j) * MS;  // T^{16j}
    __shared__ float Bl[NL * NL];
    __shared__ float At[NL][36];
    for (int idx = t; idx < MS / 4; idx += 256)
        ((float4*)Bl)[idx] = ((const float4*)Bm)[idx];
    for (int idx = t; idx < 32 * NL; idx += 256) {
        int m = idx >> 7, kk = idx & 127;
        At[kk][m] = lat0[(size_t)(r0 + m) * NL + kk];
    }
    __syncthreads();
    int jc = t & 127, rg = t >> 7;
    float acc[16];
#pragma unroll
    for (int q = 0; q < 16; ++q) acc[q] = 0.f;
#pragma unroll 2
    for (int kk = 0; kk < NL; ++kk) {
        float bv = Bl[kk * NL + jc];
        const f32x4_t* ap = (const f32x4_t*)&At[kk][rg * 16];
        f32x4_t a0 = ap[0], a1 = ap[1], a2 = ap[2], a3 = ap[3];
        acc[0] += a0[0] * bv;  acc[1] += a0[1] * bv;
        acc[2] += a0[2] * bv;  acc[3] += a0[3] * bv;
        acc[4] += a1[0] * bv;  acc[5] += a1[1] * bv;
        acc[6] += a1[2] * bv;  acc[7] += a1[3] * bv;
        acc[8] += a2[0] * bv;  acc[9] += a2[1] * bv;
        acc[10] += a2[2] * bv; acc[11] += a2[3] * bv;
        acc[12] += a3[0] * bv; acc[13] += a3[1] * bv;
        acc[14] += a3[2] * bv; acc[15] += a3[3] * bv;
    }
#pragma unroll
    for (int q = 0; q < 16; ++q)
        Cj[(size_t)(r0 + rg * 16 + q) * NL + jc] = f2bf(acc[q]);
}

// ---------------- K4: H[(n*16+a)][m] = bf16( sum_l F[n,l] * T^{a+1}[m,l] )
// grid = a(16, low bits) x ntile(32 rows of n each)
__global__ __launch_bounds__(256) void k_H(const float* __restrict__ F,
                                           const float* __restrict__ W,
                                           unsigned short* __restrict__ H) {
    int a = blockIdx.x & 15, nt = blockIdx.x >> 4;
    int n0 = nt * 32;
    const float* Tp = W + (size_t)a * MS;  // T^{a+1}
    __shared__ float TpT[NL * 129];        // TpT[l][m] = Tp[m][l], 66 KB
    __shared__ float Ft[NL][36];           // Ft[l][nn] = F[n0+nn][l]
    int t = threadIdx.x;
    for (int idx = t; idx < MS; idx += 256) {
        int m = idx >> 7, l = idx & 127;
        TpT[l * 129 + m] = Tp[idx];
    }
    for (int idx = t; idx < 32 * NL; idx += 256) {
        int nn = idx >> 7, l = idx & 127;
        Ft[l][nn] = F[(size_t)(n0 + nn) * NL + l];
    }
    __syncthreads();
    int m = t & 127, rg = t >> 7;
    float acc[16];
#pragma unroll
    for (int q = 0; q < 16; ++q) acc[q] = 0.f;
#pragma unroll 2
    for (int l = 0; l < NL; ++l) {
        float bv = TpT[l * 129 + m];
        const f32x4_t* ap = (const f32x4_t*)&Ft[l][rg * 16];
        f32x4_t a0 = ap[0], a1 = ap[1], a2 = ap[2], a3 = ap[3];
        acc[0] += a0[0] * bv;  acc[1] += a0[1] * bv;
        acc[2] += a0[2] * bv;  acc[3] += a0[3] * bv;
        acc[4] += a1[0] * bv;  acc[5] += a1[1] * bv;
        acc[6] += a1[2] * bv;  acc[7] += a1[3] * bv;
        acc[8] += a2[0] * bv;  acc[9] += a2[1] * bv;
        acc[10] += a2[2] * bv; acc[11] += a2[3] * bv;
        acc[12] += a3[0] * bv; acc[13] += a3[1] * bv;
        acc[14] += a3[2] * bv; acc[15] += a3[3] * bv;
    }
#pragma unroll
    for (int q = 0; q < 16; ++q) {
        int n = n0 + rg * 16 + q;
        H[((size_t)n * 16 + a) * NL + m] = f2bf(acc[q]);
    }
}

// ---------------- K5: out-tiles = C_j @ H^T (bf16 MFMA, NT) ---------------
// grid = j(16) x bt(2) x ct(128); block 256 (4 waves), 128x128 tile, K=128
__global__ __launch_bounds__(256) void k_main(const unsigned short* __restrict__ C,
                                              const unsigned short* __restrict__ H,
                                              float* __restrict__ out) {
    int bid = blockIdx.x;
    int ct = bid & 127;
    int bt = (bid >> 7) & 1;
    int j = bid >> 8;

    __shared__ __align__(16) char lA[128 * 256];  // swizzled bf16 [128][128]
    __shared__ __align__(16) char lB[128 * 256];

    int t = threadIdx.x;
    const unsigned short* Ag = C + (size_t)j * BB * NL + (size_t)(bt * 128) * NL;
    const unsigned short* Bg = H + (size_t)(ct * 128) * NL;

    for (int i = t; i < 2048; i += 256) {
        int row = i >> 4, c = i & 15;
        int sw = (c * 16) ^ ((row & 7) << 4);
        *(bf16x8_t*)(lA + row * 256 + sw) =
            *(const bf16x8_t*)(Ag + (size_t)row * NL + c * 8);
        *(bf16x8_t*)(lB + row * 256 + sw) =
            *(const bf16x8_t*)(Bg + (size_t)row * NL + c * 8);
    }
    __syncthreads();

    int w = t >> 6, lane = t & 63;
    int wb = (w >> 1) * 64;  // wave b-offset in tile
    int wc = (w & 1) * 64;   // wave col-offset in tile
    int r = lane & 15, g = lane >> 4;

    f32x4_t acc[4][4];
#pragma unroll
    for (int m = 0; m < 4; ++m)
#pragma unroll
        for (int n = 0; n < 4; ++n) acc[m][n] = (f32x4_t){0.f, 0.f, 0.f, 0.f};

#pragma unroll
    for (int kk = 0; kk < 4; ++kk) {
        int c16 = kk * 4 + g;
        bf16x8_t av[4], bv[4];
#pragma unroll
        for (int m = 0; m < 4; ++m) {
            int rowA = wb + m * 16 + r;
            av[m] = *(const bf16x8_t*)(lA + rowA * 256 + ((c16 * 16) ^ ((rowA & 7) << 4)));
            int rowB = wc + m * 16 + r;
            bv[m] = *(const bf16x8_t*)(lB + rowB * 256 + ((c16 * 16) ^ ((rowB & 7) << 4)));
        }
#pragma unroll
        for (int m = 0; m < 4; ++m)
#pragma unroll
            for (int n = 0; n < 4; ++n)
                acc[m][n] = __builtin_amdgcn_mfma_f32_16x16x32_bf16(av[m], bv[n], acc[m][n], 0, 0, 0);
    }

    // store: out[b][n_glob][s] with s = 16*j + (col & 15)
#pragma unroll
    for (int m = 0; m < 4; ++m) {
#pragma unroll
        for (int n = 0; n < 4; ++n) {
#pragma unroll
            for (int q = 0; q < 4; ++q) {
                int brow = bt * 128 + wb + m * 16 + g * 4 + q;
                int col = ct * 128 + wc + n * 16 + r;  // col&15 == r
                out[(size_t)brow * (NIN * NSTEPS) + (size_t)(col >> 4) * NSTEPS + 16 * j + (col & 15)] =
                    acc[m][n][q];
            }
        }
    }
}

extern "C" void kernel_launch(void* const* d_in, const int* in_sizes, int n_in,
                              void* d_out, int out_size, void* d_ws, size_t ws_size,
                              hipStream_t stream) {
    const float* x = (const float*)d_in[0];
    const float* tf = (const float*)d_in[1];
    const float* tr = (const float*)d_in[2];
    float* out = (float*)d_out;

    // workspace layout
    float* W = (float*)d_ws;                 // 30 slots: T^1..T^16 (0..15), T^{32j'} chain (16..29)
    float* lat0 = W + 30 * (size_t)MS;       // [256][128] f32
    unsigned short* C = (unsigned short*)(lat0 + (size_t)BB * NL);  // [16][256][128] bf16
    unsigned short* H = C + (size_t)16 * BB * NL;                   // [16384][128] bf16

    // W slot 0 = T^1
    hipMemcpyAsync(W, tr, MS * sizeof(float), hipMemcpyDeviceToDevice, stream);

    k_init<<<BB, 128, 0, stream>>>(x, tf, lat0);

    // T-chain: T^2 ; T^3,T^4 ; T^5..8 ; T^9..16  (slots 1..15)
    k_pmm<<<4, 256, 0, stream>>>(W, W, W + 1 * (size_t)MS);
    k_pmm<<<8, 256, 0, stream>>>(W, W + 1 * (size_t)MS, W + 2 * (size_t)MS);
    k_pmm<<<16, 256, 0, stream>>>(W, W + 3 * (size_t)MS, W + 4 * (size_t)MS);
    k_pmm<<<32, 256, 0, stream>>>(W, W + 7 * (size_t)MS, W + 8 * (size_t)MS);
    // U-chain: V_j = T^{16j} at slot 14+j (V1 = slot 15 = T^16)
    k_pmm<<<4, 256, 0, stream>>>(W + 15 * (size_t)MS, W + 15 * (size_t)MS, W + 16 * (size_t)MS);
    k_pmm<<<8, 256, 0, stream>>>(W + 15 * (size_t)MS, W + 16 * (size_t)MS, W + 17 * (size_t)MS);
    k_pmm<<<16, 256, 0, stream>>>(W + 15 * (size_t)MS, W + 18 * (size_t)MS, W + 19 * (size_t)MS);
    k_pmm<<<28, 256, 0, stream>>>(W + 15 * (size_t)MS, W + 22 * (size_t)MS, W + 23 * (size_t)MS);

    k_H<<<512, 256, 0, stream>>>(tf, W, H);
    k_C<<<128, 256, 0, stream>>>(lat0, W, C);
    k_main<<<4096, 256, 0, stream>>>(C, H, out);
}